// Round 1
// baseline (128.217 us; speedup 1.0000x reference)
//
#include <hip/hip_runtime.h>
#include <hip/hip_bf16.h>
#include <math.h>

// Problem constants
#define NN 96
#define SS 4096
#define PP 4096
#define PH 1024
#define PHH 512
#define TP 3267            // TOTAL_PARAMS
#define KC_SPLIT 16
#define KCHUNK 256         // 4096 / 16

__device__ __forceinline__ float stp(float x) {
    // softplus(x)/6
    float sp = (x > 15.0f) ? x : log1pf(expf(x));
    return sp * (1.0f / 6.0f);
}

__device__ __forceinline__ float sin_w0(float x) {
    // sin(30*x) via Cody-Waite reduction to revolutions + v_sin_f32
    constexpr double Cd = 30.0 / 6.283185307179586476925286766559; // 30/(2pi)
    constexpr float C_hi = (float)Cd;
    constexpr float C_lo = (float)(Cd - (double)C_hi);
    float t = x * C_hi;
    float k = rintf(t);
    float r = fmaf(x, C_hi, -k);   // exact cancellation (fma)
    r = fmaf(x, C_lo, r);
    return __builtin_amdgcn_sinf(r);  // sin(2*pi*r)
}

// ---------------- Kernel 1: build zT[p][n] (transposed z) ----------------
__global__ __launch_bounds__(256) void z_kernel(
    const float* __restrict__ loc, const float* __restrict__ log_scale,
    const float* __restrict__ h_loc, const float* __restrict__ h_ls,
    const float* __restrict__ hh_loc, const float* __restrict__ hh_ls,
    const float* __restrict__ eps, const float* __restrict__ h_eps,
    const float* __restrict__ hh_eps,
    const int* __restrict__ h_gi, const int* __restrict__ hh_gi,
    float* __restrict__ zT)
{
    int t = blockIdx.x * 256 + threadIdx.x;      // t < 96*4096
    int n = t % NN;
    int p = t / NN;
    int idx = n * PP + p;
    float s = loc[idx] + eps[idx] * stp(log_scale[idx]);
    int g  = h_gi[p];
    int gh = (n >> 4) * PH + g;
    float hs = h_loc[gh] + h_eps[gh] * stp(h_ls[gh]);
    int gg = hh_gi[p];
    float hhs = hh_loc[gg] + hh_eps[gg] * stp(hh_ls[gg]);
    zT[p * NN + n] = s + hs + hhs;
}

// ---------------- Kernel 2: partials[kc][n][j] = sum_k z[n][k]*W_map[k][j] ----------------
// grid: 13 j-tiles * 16 k-chunks * 3 n-groups = 624 blocks of 256
__global__ __launch_bounds__(256) void gemm_kernel(
    const float* __restrict__ Wm, const float* __restrict__ zT,
    float* __restrict__ partials)
{
    int b  = blockIdx.x;
    int ng = b % 3;              // fastest: blocks sharing W-chunk adjacent -> L2 reuse
    int kc = (b / 3) % KC_SPLIT;
    int jt = b / (3 * KC_SPLIT);
    int j = jt * 256 + threadIdx.x;
    if (j >= TP) return;
    int n0 = ng * 32;

    float acc[32];
#pragma unroll
    for (int i = 0; i < 32; ++i) acc[i] = 0.0f;

    const float* wp = Wm + (size_t)(kc * KCHUNK) * TP + j;
    const float* zp = zT + (size_t)(kc * KCHUNK) * NN + n0;   // block-uniform -> s_load

    for (int k = 0; k < KCHUNK; ++k) {
        float w = *wp;            // coalesced vector load (one dword/lane)
        wp += TP;
#pragma unroll
        for (int i = 0; i < 32; ++i)
            acc[i] = fmaf(zp[i], w, acc[i]);   // s_z * v_w
        zp += NN;
    }

    float* pp = partials + ((size_t)(kc * NN + n0)) * TP + j;
#pragma unroll
    for (int i = 0; i < 32; ++i) { *pp = acc[i]; pp += TP; }
}

// ---------------- Kernel 3: params[n][j] = b_map[j] + sum_kc partials ----------------
__global__ __launch_bounds__(256) void reduce_kernel(
    const float* __restrict__ partials, const float* __restrict__ b_map,
    float* __restrict__ params)
{
    int t = blockIdx.x * 256 + threadIdx.x;
    if (t >= NN * TP) return;
    int j = t % TP;
    int n = t / TP;
    float a = b_map[j];
#pragma unroll
    for (int kc = 0; kc < KC_SPLIT; ++kc)
        a += partials[((size_t)(kc * NN + n)) * TP + j];
    params[(size_t)n * TP + j] = a;
}

// ---------------- Kernel 4: per-sample SIREN MLP ----------------
// grid: (16 s-chunks, 96 n), 256 threads; weights via scalar loads (block-uniform)
__global__ __launch_bounds__(256) void mlp_kernel(
    const float* __restrict__ x, const float* __restrict__ params,
    float* __restrict__ out)
{
    int n = blockIdx.y;
    int s = blockIdx.x * 256 + threadIdx.x;
    const float* pr = params + (size_t)n * TP;

    float h[32];
    const float4* xv = (const float4*)(x + ((size_t)n * SS + s) * 32);
#pragma unroll
    for (int i = 0; i < 8; ++i) {
        float4 v = xv[i];
        h[4*i+0] = v.x; h[4*i+1] = v.y; h[4*i+2] = v.z; h[4*i+3] = v.w;
    }

#pragma unroll 1
    for (int L = 0; L < 3; ++L) {
        const float* lp = pr + L * 1056;
        float t[32];
#pragma unroll
        for (int e = 0; e < 32; ++e) t[e] = lp[e];          // bias (s_load)
#pragma unroll
        for (int d = 0; d < 32; ++d) {
            const float* wrow = lp + 32 + d * 32;
            float hd = h[d];
#pragma unroll
            for (int e = 0; e < 32; ++e)
                t[e] = fmaf(hd, wrow[e], t[e]);             // v_fma with s-operand
        }
#pragma unroll
        for (int e = 0; e < 32; ++e) h[e] = sin_w0(t[e]);
    }

    // last layer 32 -> 3, no activation
    const float* lp = pr + 3168;
    float t3[3];
#pragma unroll
    for (int e = 0; e < 3; ++e) t3[e] = lp[e];
#pragma unroll
    for (int d = 0; d < 32; ++d) {
        float hd = h[d];
#pragma unroll
        for (int e = 0; e < 3; ++e)
            t3[e] = fmaf(hd, lp[3 + d * 3 + e], t3[e]);
    }

    float* op = out + ((size_t)n * SS + s) * 3;
    op[0] = t3[0]; op[1] = t3[1]; op[2] = t3[2];
}

extern "C" void kernel_launch(void* const* d_in, const int* in_sizes, int n_in,
                              void* d_out, int out_size, void* d_ws, size_t ws_size,
                              hipStream_t stream)
{
    const float* x        = (const float*)d_in[0];
    const float* loc      = (const float*)d_in[1];
    const float* log_sc   = (const float*)d_in[2];
    const float* h_loc    = (const float*)d_in[3];
    const float* h_ls     = (const float*)d_in[4];
    const float* hh_loc   = (const float*)d_in[5];
    const float* hh_ls    = (const float*)d_in[6];
    const float* eps      = (const float*)d_in[7];
    const float* h_eps    = (const float*)d_in[8];
    const float* hh_eps   = (const float*)d_in[9];
    const float* W_map    = (const float*)d_in[10];
    const float* b_map    = (const float*)d_in[11];
    const int*   h_gi     = (const int*)d_in[12];
    const int*   hh_gi    = (const int*)d_in[13];
    float* out = (float*)d_out;

    // workspace layout (floats)
    float* zT       = (float*)d_ws;                       // 4096*96      = 393,216
    float* partials = zT + (size_t)PP * NN;               // 16*96*3267   = 5,018,112
    float* params   = partials + (size_t)KC_SPLIT * NN * TP; // 96*3267  = 313,632

    z_kernel<<<(NN * PP) / 256, 256, 0, stream>>>(
        loc, log_sc, h_loc, h_ls, hh_loc, hh_ls, eps, h_eps, hh_eps,
        h_gi, hh_gi, zT);

    gemm_kernel<<<13 * KC_SPLIT * 3, 256, 0, stream>>>(W_map, zT, partials);

    reduce_kernel<<<(NN * TP + 255) / 256, 256, 0, stream>>>(partials, b_map, params);

    mlp_kernel<<<dim3(16, NN), 256, 0, stream>>>(x, params, out);
}

// Round 2
// 115.244 us; speedup vs baseline: 1.1126x; 1.1126x over previous
//
#include <hip/hip_runtime.h>
#include <hip/hip_bf16.h>
#include <math.h>

// Problem constants
#define NN 96
#define SS 4096
#define PP 4096
#define PH 1024
#define PHH 512
#define TP 3267            // TOTAL_PARAMS
#define KC_SPLIT 16
#define KCHUNK 256         // 4096 / 16
#define NG 6               // n-groups in gemm
#define NACC 16            // accumulators per thread in gemm

__device__ __forceinline__ float stp(float x) {
    // softplus(x)/6
    float sp = (x > 15.0f) ? x : log1pf(expf(x));
    return sp * (1.0f / 6.0f);
}

__device__ __forceinline__ float sin_w0(float x) {
    // sin(30*x) via Cody-Waite reduction to revolutions + v_sin_f32
    constexpr double Cd = 30.0 / 6.283185307179586476925286766559; // 30/(2pi)
    constexpr float C_hi = (float)Cd;
    constexpr float C_lo = (float)(Cd - (double)C_hi);
    float t = x * C_hi;
    float k = rintf(t);
    float r = fmaf(x, C_hi, -k);   // exact cancellation (fma)
    r = fmaf(x, C_lo, r);
    return __builtin_amdgcn_sinf(r);  // sin(2*pi*r)
}

// ---------------- Kernel 1: build zT[p][n] (transposed z) ----------------
__global__ __launch_bounds__(256) void z_kernel(
    const float* __restrict__ loc, const float* __restrict__ log_scale,
    const float* __restrict__ h_loc, const float* __restrict__ h_ls,
    const float* __restrict__ hh_loc, const float* __restrict__ hh_ls,
    const float* __restrict__ eps, const float* __restrict__ h_eps,
    const float* __restrict__ hh_eps,
    const int* __restrict__ h_gi, const int* __restrict__ hh_gi,
    float* __restrict__ zT)
{
    int t = blockIdx.x * 256 + threadIdx.x;      // t < 96*4096
    int n = t % NN;
    int p = t / NN;
    int idx = n * PP + p;
    float s = loc[idx] + eps[idx] * stp(log_scale[idx]);
    int g  = h_gi[p];
    int gh = (n >> 4) * PH + g;
    float hs = h_loc[gh] + h_eps[gh] * stp(h_ls[gh]);
    int gg = hh_gi[p];
    float hhs = hh_loc[gg] + hh_eps[gg] * stp(hh_ls[gg]);
    zT[p * NN + n] = s + hs + hhs;
}

// ---------------- Kernel 2: partials[kc][n][j] = sum_k z[n][k]*W_map[k][j] ----------------
// grid: 1248 blocks = NG(6) * 208, siblings (same jt,kc) at stride 208 (0 mod 8 -> same XCD)
__global__ __launch_bounds__(256, 6) void gemm_kernel(
    const float* __restrict__ Wm, const float* __restrict__ zT,
    float* __restrict__ partials)
{
    int b = blockIdx.x;
    int jtkc = b % 208;          // 13 jt * 16 kc
    int ng   = b / 208;
    int kc = jtkc % KC_SPLIT;
    int jt = jtkc / KC_SPLIT;
    int j = jt * 256 + threadIdx.x;
    if (j >= TP) return;
    int n0 = ng * NACC;

    float acc[NACC];
#pragma unroll
    for (int i = 0; i < NACC; ++i) acc[i] = 0.0f;

    const float* wp = Wm + (size_t)(kc * KCHUNK) * TP + j;
    const float* zp = zT + (size_t)(kc * KCHUNK) * NN + n0;   // block-uniform -> s_load

#pragma unroll 4
    for (int k = 0; k < KCHUNK; ++k) {
        float w = *wp;            // coalesced vector load (one dword/lane)
        wp += TP;
#pragma unroll
        for (int i = 0; i < NACC; ++i)
            acc[i] = fmaf(zp[i], w, acc[i]);   // s_z * v_w
        zp += NN;
    }

    float* pp = partials + ((size_t)(kc * NN + n0)) * TP + j;
#pragma unroll
    for (int i = 0; i < NACC; ++i) { *pp = acc[i]; pp += TP; }
}

// ---------------- Kernel 3: params[n][j] = b_map[j] + sum_kc partials ----------------
__global__ __launch_bounds__(256) void reduce_kernel(
    const float* __restrict__ partials, const float* __restrict__ b_map,
    float* __restrict__ params)
{
    int t = blockIdx.x * 256 + threadIdx.x;
    if (t >= NN * TP) return;
    int j = t % TP;
    int n = t / TP;
    float a = b_map[j];
#pragma unroll
    for (int kc = 0; kc < KC_SPLIT; ++kc)
        a += partials[((size_t)(kc * NN + n)) * TP + j];
    params[(size_t)n * TP + j] = a;
}

// ---------------- Kernel 4: per-sample SIREN MLP, V=2 s-points/thread ----------------
// grid: (8 s-chunks, 96 n), 256 threads; weights via scalar loads (block-uniform)
__global__ __launch_bounds__(256, 3) void mlp_kernel(
    const float* __restrict__ x, const float* __restrict__ params,
    float* __restrict__ out)
{
    int n = blockIdx.y;
    int s0 = blockIdx.x * 512 + threadIdx.x;   // and s0 + 256
    const float* pr = params + (size_t)n * TP;

    float h0[32], h1[32];
    {
        const float4* xv0 = (const float4*)(x + ((size_t)n * SS + s0) * 32);
        const float4* xv1 = (const float4*)(x + ((size_t)n * SS + s0 + 256) * 32);
#pragma unroll
        for (int i = 0; i < 8; ++i) {
            float4 v0 = xv0[i];
            h0[4*i+0] = v0.x; h0[4*i+1] = v0.y; h0[4*i+2] = v0.z; h0[4*i+3] = v0.w;
            float4 v1 = xv1[i];
            h1[4*i+0] = v1.x; h1[4*i+1] = v1.y; h1[4*i+2] = v1.z; h1[4*i+3] = v1.w;
        }
    }

#pragma unroll 1
    for (int L = 0; L < 3; ++L) {
        const float* lp = pr + L * 1056;
        float t0[32], t1[32];
#pragma unroll
        for (int e = 0; e < 32; ++e) { float b = lp[e]; t0[e] = b; t1[e] = b; }
#pragma unroll
        for (int d = 0; d < 32; ++d) {
            const float* wrow = lp + 32 + d * 32;
            float hd0 = h0[d];
            float hd1 = h1[d];
#pragma unroll
            for (int e = 0; e < 32; ++e) {
                float w = wrow[e];                  // s_load (block-uniform)
                t0[e] = fmaf(hd0, w, t0[e]);
                t1[e] = fmaf(hd1, w, t1[e]);
            }
        }
#pragma unroll
        for (int e = 0; e < 32; ++e) { h0[e] = sin_w0(t0[e]); h1[e] = sin_w0(t1[e]); }
    }

    // last layer 32 -> 3, no activation
    const float* lp = pr + 3168;
    float a0[3], a1[3];
#pragma unroll
    for (int e = 0; e < 3; ++e) { float b = lp[e]; a0[e] = b; a1[e] = b; }
#pragma unroll
    for (int d = 0; d < 32; ++d) {
        float hd0 = h0[d];
        float hd1 = h1[d];
#pragma unroll
        for (int e = 0; e < 3; ++e) {
            float w = lp[3 + d * 3 + e];
            a0[e] = fmaf(hd0, w, a0[e]);
            a1[e] = fmaf(hd1, w, a1[e]);
        }
    }

    float* op0 = out + ((size_t)n * SS + s0) * 3;
    float* op1 = out + ((size_t)n * SS + s0 + 256) * 3;
    op0[0] = a0[0]; op0[1] = a0[1]; op0[2] = a0[2];
    op1[0] = a1[0]; op1[1] = a1[1]; op1[2] = a1[2];
}

extern "C" void kernel_launch(void* const* d_in, const int* in_sizes, int n_in,
                              void* d_out, int out_size, void* d_ws, size_t ws_size,
                              hipStream_t stream)
{
    const float* x        = (const float*)d_in[0];
    const float* loc      = (const float*)d_in[1];
    const float* log_sc   = (const float*)d_in[2];
    const float* h_loc    = (const float*)d_in[3];
    const float* h_ls     = (const float*)d_in[4];
    const float* hh_loc   = (const float*)d_in[5];
    const float* hh_ls    = (const float*)d_in[6];
    const float* eps      = (const float*)d_in[7];
    const float* h_eps    = (const float*)d_in[8];
    const float* hh_eps   = (const float*)d_in[9];
    const float* W_map    = (const float*)d_in[10];
    const float* b_map    = (const float*)d_in[11];
    const int*   h_gi     = (const int*)d_in[12];
    const int*   hh_gi    = (const int*)d_in[13];
    float* out = (float*)d_out;

    // workspace layout (floats)
    float* zT       = (float*)d_ws;                       // 4096*96      = 393,216
    float* partials = zT + (size_t)PP * NN;               // 16*96*3267   = 5,018,112
    float* params   = partials + (size_t)KC_SPLIT * NN * TP; // 96*3267  = 313,632

    z_kernel<<<(NN * PP) / 256, 256, 0, stream>>>(
        loc, log_sc, h_loc, h_ls, hh_loc, hh_ls, eps, h_eps, hh_eps,
        h_gi, hh_gi, zT);

    gemm_kernel<<<NG * 208, 256, 0, stream>>>(W_map, zT, partials);

    reduce_kernel<<<(NN * TP + 255) / 256, 256, 0, stream>>>(partials, b_map, params);

    mlp_kernel<<<dim3(8, NN), 256, 0, stream>>>(x, params, out);
}

// Round 3
// 112.330 us; speedup vs baseline: 1.1414x; 1.0259x over previous
//
#include <hip/hip_runtime.h>
#include <hip/hip_bf16.h>
#include <math.h>

// Problem constants
#define NN 96
#define SS 4096
#define PP 4096
#define PH 1024
#define PHH 512
#define TP 3267            // TOTAL_PARAMS
#define KC_SPLIT 16
#define KCHUNK 256         // 4096 / 16
#define NG 6               // n-groups in gemm
#define NACC 16            // accumulators per thread in gemm

__device__ __forceinline__ float stp(float x) {
    // softplus(x)/6
    float sp = (x > 15.0f) ? x : log1pf(expf(x));
    return sp * (1.0f / 6.0f);
}

__device__ __forceinline__ float sin_w0(float x) {
    // sin(30*x) via Cody-Waite reduction to revolutions + v_sin_f32
    constexpr double Cd = 30.0 / 6.283185307179586476925286766559; // 30/(2pi)
    constexpr float C_hi = (float)Cd;
    constexpr float C_lo = (float)(Cd - (double)C_hi);
    float t = x * C_hi;
    float k = rintf(t);
    float r = fmaf(x, C_hi, -k);   // exact cancellation (fma)
    r = fmaf(x, C_lo, r);
    return __builtin_amdgcn_sinf(r);  // sin(2*pi*r)
}

// ---------------- Kernel 1: build zT[p][n] (transposed z) ----------------
__global__ __launch_bounds__(256) void z_kernel(
    const float* __restrict__ loc, const float* __restrict__ log_scale,
    const float* __restrict__ h_loc, const float* __restrict__ h_ls,
    const float* __restrict__ hh_loc, const float* __restrict__ hh_ls,
    const float* __restrict__ eps, const float* __restrict__ h_eps,
    const float* __restrict__ hh_eps,
    const int* __restrict__ h_gi, const int* __restrict__ hh_gi,
    float* __restrict__ zT)
{
    int t = blockIdx.x * 256 + threadIdx.x;      // t < 96*4096
    int n = t % NN;
    int p = t / NN;
    int idx = n * PP + p;
    float s = loc[idx] + eps[idx] * stp(log_scale[idx]);
    int g  = h_gi[p];
    int gh = (n >> 4) * PH + g;
    float hs = h_loc[gh] + h_eps[gh] * stp(h_ls[gh]);
    int gg = hh_gi[p];
    float hhs = hh_loc[gg] + hh_eps[gg] * stp(hh_ls[gg]);
    zT[p * NN + n] = s + hs + hhs;
}

// ---------------- Kernel 2: partials[kc][n][j] = sum_k z[n][k]*W_map[k][j] ----------------
// grid: 1248 blocks = NG(6) * 208, siblings (same jt,kc) at stride 208 (0 mod 8 -> same XCD)
__global__ __launch_bounds__(256, 6) void gemm_kernel(
    const float* __restrict__ Wm, const float* __restrict__ zT,
    float* __restrict__ partials)
{
    int b = blockIdx.x;
    int jtkc = b % 208;          // 13 jt * 16 kc
    int ng   = b / 208;
    int kc = jtkc % KC_SPLIT;
    int jt = jtkc / KC_SPLIT;
    int j = jt * 256 + threadIdx.x;
    if (j >= TP) return;
    int n0 = ng * NACC;

    float acc[NACC];
#pragma unroll
    for (int i = 0; i < NACC; ++i) acc[i] = 0.0f;

    const float* wp = Wm + (size_t)(kc * KCHUNK) * TP + j;
    const float* zp = zT + (size_t)(kc * KCHUNK) * NN + n0;   // block-uniform -> s_load

#pragma unroll 4
    for (int k = 0; k < KCHUNK; ++k) {
        float w = *wp;            // coalesced vector load (one dword/lane)
        wp += TP;
#pragma unroll
        for (int i = 0; i < NACC; ++i)
            acc[i] = fmaf(zp[i], w, acc[i]);   // s_z * v_w
        zp += NN;
    }

    float* pp = partials + ((size_t)(kc * NN + n0)) * TP + j;
#pragma unroll
    for (int i = 0; i < NACC; ++i) { *pp = acc[i]; pp += TP; }
}

// ---------------- Kernel 3: params[n][j] = b_map[j] + sum_kc partials ----------------
__global__ __launch_bounds__(256) void reduce_kernel(
    const float* __restrict__ partials, const float* __restrict__ b_map,
    float* __restrict__ params)
{
    int t = blockIdx.x * 256 + threadIdx.x;
    if (t >= NN * TP) return;
    int j = t % TP;
    int n = t / TP;
    float a = b_map[j];
#pragma unroll
    for (int kc = 0; kc < KC_SPLIT; ++kc)
        a += partials[((size_t)(kc * NN + n)) * TP + j];
    params[(size_t)n * TP + j] = a;
}

// ---------------- Kernel 4: per-sample SIREN MLP, LDS-staged weights ----------------
// grid: (8 s-chunks, 96 n), 256 threads, V=2 s-points/thread.
// Weights staged once per block into LDS; read as wave-uniform ds_read_b128
// broadcasts (conflict-free), freeing the scalar pipe / s_waitcnt stalls.
__global__ __launch_bounds__(256, 3) void mlp_kernel(
    const float* __restrict__ x, const float* __restrict__ params,
    float* __restrict__ out)
{
    __shared__ __align__(16) float lds[TP + 1];

    int n = blockIdx.y;
    int s0 = blockIdx.x * 512 + threadIdx.x;   // and s0 + 256
    const float* pr = params + (size_t)n * TP;

    // stage params[n] -> LDS (coalesced, 13 iters)
    for (int i = threadIdx.x; i < TP; i += 256) lds[i] = pr[i];

    float h0[32], h1[32];
    {
        const float4* xv0 = (const float4*)(x + ((size_t)n * SS + s0) * 32);
        const float4* xv1 = (const float4*)(x + ((size_t)n * SS + s0 + 256) * 32);
#pragma unroll
        for (int i = 0; i < 8; ++i) {
            float4 v0 = xv0[i];
            h0[4*i+0] = v0.x; h0[4*i+1] = v0.y; h0[4*i+2] = v0.z; h0[4*i+3] = v0.w;
            float4 v1 = xv1[i];
            h1[4*i+0] = v1.x; h1[4*i+1] = v1.y; h1[4*i+2] = v1.z; h1[4*i+3] = v1.w;
        }
    }

    __syncthreads();

#pragma unroll 1
    for (int L = 0; L < 3; ++L) {
        const float* lp = lds + L * 1056;
        float t0[32], t1[32];
#pragma unroll
        for (int e = 0; e < 32; ++e) { float b = lp[e]; t0[e] = b; t1[e] = b; }
#pragma unroll 4
        for (int d = 0; d < 32; ++d) {
            const float4* w4 = (const float4*)(lp + 32 + d * 32);
            float hd0 = h0[d];
            float hd1 = h1[d];
#pragma unroll
            for (int e4 = 0; e4 < 8; ++e4) {
                float4 w = w4[e4];                  // ds_read_b128 broadcast
                t0[4*e4+0] = fmaf(hd0, w.x, t0[4*e4+0]);
                t1[4*e4+0] = fmaf(hd1, w.x, t1[4*e4+0]);
                t0[4*e4+1] = fmaf(hd0, w.y, t0[4*e4+1]);
                t1[4*e4+1] = fmaf(hd1, w.y, t1[4*e4+1]);
                t0[4*e4+2] = fmaf(hd0, w.z, t0[4*e4+2]);
                t1[4*e4+2] = fmaf(hd1, w.z, t1[4*e4+2]);
                t0[4*e4+3] = fmaf(hd0, w.w, t0[4*e4+3]);
                t1[4*e4+3] = fmaf(hd1, w.w, t1[4*e4+3]);
            }
        }
#pragma unroll
        for (int e = 0; e < 32; ++e) { h0[e] = sin_w0(t0[e]); h1[e] = sin_w0(t1[e]); }
    }

    // last layer 32 -> 3, no activation (small: scalar LDS broadcasts)
    const float* lp3 = lds + 3168;
    float a0[3], a1[3];
#pragma unroll
    for (int e = 0; e < 3; ++e) { float b = lp3[e]; a0[e] = b; a1[e] = b; }
#pragma unroll
    for (int d = 0; d < 32; ++d) {
        float hd0 = h0[d];
        float hd1 = h1[d];
#pragma unroll
        for (int e = 0; e < 3; ++e) {
            float w = lp3[3 + d * 3 + e];
            a0[e] = fmaf(hd0, w, a0[e]);
            a1[e] = fmaf(hd1, w, a1[e]);
        }
    }

    float* op0 = out + ((size_t)n * SS + s0) * 3;
    float* op1 = out + ((size_t)n * SS + s0 + 256) * 3;
    op0[0] = a0[0]; op0[1] = a0[1]; op0[2] = a0[2];
    op1[0] = a1[0]; op1[1] = a1[1]; op1[2] = a1[2];
}

extern "C" void kernel_launch(void* const* d_in, const int* in_sizes, int n_in,
                              void* d_out, int out_size, void* d_ws, size_t ws_size,
                              hipStream_t stream)
{
    const float* x        = (const float*)d_in[0];
    const float* loc      = (const float*)d_in[1];
    const float* log_sc   = (const float*)d_in[2];
    const float* h_loc    = (const float*)d_in[3];
    const float* h_ls     = (const float*)d_in[4];
    const float* hh_loc   = (const float*)d_in[5];
    const float* hh_ls    = (const float*)d_in[6];
    const float* eps      = (const float*)d_in[7];
    const float* h_eps    = (const float*)d_in[8];
    const float* hh_eps   = (const float*)d_in[9];
    const float* W_map    = (const float*)d_in[10];
    const float* b_map    = (const float*)d_in[11];
    const int*   h_gi     = (const int*)d_in[12];
    const int*   hh_gi    = (const int*)d_in[13];
    float* out = (float*)d_out;

    // workspace layout (floats)
    float* zT       = (float*)d_ws;                       // 4096*96      = 393,216
    float* partials = zT + (size_t)PP * NN;               // 16*96*3267   = 5,018,112
    float* params   = partials + (size_t)KC_SPLIT * NN * TP; // 96*3267  = 313,632

    z_kernel<<<(NN * PP) / 256, 256, 0, stream>>>(
        loc, log_sc, h_loc, h_ls, hh_loc, hh_ls, eps, h_eps, hh_eps,
        h_gi, hh_gi, zT);

    gemm_kernel<<<NG * 208, 256, 0, stream>>>(W_map, zT, partials);

    reduce_kernel<<<(NN * TP + 255) / 256, 256, 0, stream>>>(partials, b_map, params);

    mlp_kernel<<<dim3(8, NN), 256, 0, stream>>>(x, params, out);
}

// Round 4
// 107.623 us; speedup vs baseline: 1.1913x; 1.0437x over previous
//
#include <hip/hip_runtime.h>
#include <hip/hip_bf16.h>
#include <math.h>

// Problem constants
#define NN 96
#define SS 4096
#define PP 4096
#define PH 1024
#define PHH 512
#define TP 3267            // TOTAL_PARAMS
#define KC_SPLIT 16
#define KCHUNK 256         // 4096 / 16
#define NG 6               // n-groups in gemm
#define NACC 16            // accumulators per thread in gemm

__device__ __forceinline__ float stp(float x) {
    // softplus(x)/6
    float sp = (x > 15.0f) ? x : log1pf(expf(x));
    return sp * (1.0f / 6.0f);
}

__device__ __forceinline__ float sin_w0(float x) {
    // sin(30*x) via Cody-Waite reduction to revolutions + v_sin_f32
    constexpr double Cd = 30.0 / 6.283185307179586476925286766559; // 30/(2pi)
    constexpr float C_hi = (float)Cd;
    constexpr float C_lo = (float)(Cd - (double)C_hi);
    float t = x * C_hi;
    float k = rintf(t);
    float r = fmaf(x, C_hi, -k);   // exact cancellation (fma)
    r = fmaf(x, C_lo, r);
    return __builtin_amdgcn_sinf(r);  // sin(2*pi*r)
}

// ---------------- Kernel 1: build zT[p][n] (transposed z) ----------------
__global__ __launch_bounds__(256) void z_kernel(
    const float* __restrict__ loc, const float* __restrict__ log_scale,
    const float* __restrict__ h_loc, const float* __restrict__ h_ls,
    const float* __restrict__ hh_loc, const float* __restrict__ hh_ls,
    const float* __restrict__ eps, const float* __restrict__ h_eps,
    const float* __restrict__ hh_eps,
    const int* __restrict__ h_gi, const int* __restrict__ hh_gi,
    float* __restrict__ zT)
{
    int t = blockIdx.x * 256 + threadIdx.x;      // t < 96*4096
    int n = t % NN;
    int p = t / NN;
    int idx = n * PP + p;
    float s = loc[idx] + eps[idx] * stp(log_scale[idx]);
    int g  = h_gi[p];
    int gh = (n >> 4) * PH + g;
    float hs = h_loc[gh] + h_eps[gh] * stp(h_ls[gh]);
    int gg = hh_gi[p];
    float hhs = hh_loc[gg] + hh_eps[gg] * stp(hh_ls[gg]);
    zT[p * NN + n] = s + hs + hhs;
}

// ---------------- Kernel 2: partials[kc][n][j] = sum_k z[n][k]*W_map[k][j] ----------------
// grid: 1248 blocks = NG(6) * 208, siblings (same jt,kc) at stride 208 (0 mod 8 -> same XCD)
// W loads explicitly double-buffered 8-deep to cover HBM latency.
__global__ __launch_bounds__(256, 6) void gemm_kernel(
    const float* __restrict__ Wm, const float* __restrict__ zT,
    float* __restrict__ partials)
{
    int b = blockIdx.x;
    int jtkc = b % 208;          // 13 jt * 16 kc
    int ng   = b / 208;
    int kc = jtkc % KC_SPLIT;
    int jt = jtkc / KC_SPLIT;
    int j = jt * 256 + threadIdx.x;
    if (j >= TP) return;
    int n0 = ng * NACC;

    float acc[NACC];
#pragma unroll
    for (int i = 0; i < NACC; ++i) acc[i] = 0.0f;

    const float* wp = Wm + (size_t)(kc * KCHUNK) * TP + j;
    const float* zp = zT + (size_t)(kc * KCHUNK) * NN + n0;   // block-uniform -> s_load

    float wcur[8], wnext[8];
#pragma unroll
    for (int u = 0; u < 8; ++u) wcur[u] = wp[(size_t)u * TP];

#pragma unroll 1
    for (int p = 0; p < KCHUNK / 8 - 1; ++p) {
        const float* wpn = wp + (size_t)(p + 1) * 8 * TP;
#pragma unroll
        for (int u = 0; u < 8; ++u) wnext[u] = wpn[(size_t)u * TP];  // in flight over FMAs
        const float* zr = zp + (size_t)p * 8 * NN;
#pragma unroll
        for (int u = 0; u < 8; ++u) {
            float w = wcur[u];
#pragma unroll
            for (int i = 0; i < NACC; ++i)
                acc[i] = fmaf(zr[u * NN + i], w, acc[i]);   // s_z * v_w
        }
#pragma unroll
        for (int u = 0; u < 8; ++u) wcur[u] = wnext[u];
    }
    {   // last phase
        const float* zr = zp + (size_t)(KCHUNK - 8) * NN;
#pragma unroll
        for (int u = 0; u < 8; ++u) {
            float w = wcur[u];
#pragma unroll
            for (int i = 0; i < NACC; ++i)
                acc[i] = fmaf(zr[u * NN + i], w, acc[i]);
        }
    }

    float* pp = partials + ((size_t)(kc * NN + n0)) * TP + j;
#pragma unroll
    for (int i = 0; i < NACC; ++i) { *pp = acc[i]; pp += TP; }
}

// ---------------- Kernel 3: params[n][j] = b_map[j] + sum_kc partials ----------------
__global__ __launch_bounds__(256) void reduce_kernel(
    const float* __restrict__ partials, const float* __restrict__ b_map,
    float* __restrict__ params)
{
    int t = blockIdx.x * 256 + threadIdx.x;
    if (t >= NN * TP) return;
    int j = t % TP;
    int n = t / TP;
    float a = b_map[j];
#pragma unroll
    for (int kc = 0; kc < KC_SPLIT; ++kc)
        a += partials[((size_t)(kc * NN + n)) * TP + j];
    params[(size_t)n * TP + j] = a;
}

// ---------------- Kernel 4: per-sample SIREN MLP, V=1, s_load weights ----------------
// 768 blocks x 512 threads. Block mapping makes co-resident blocks (b, b+256,
// b+512 -> same CU under mod-256 round-robin dispatch) share the same n, so the
// 13KB weight row stays hot in the per-CU scalar cache instead of thrashing.
__global__ __launch_bounds__(512) void mlp_kernel(
    const float* __restrict__ x, const float* __restrict__ params,
    float* __restrict__ out)
{
    int b = blockIdx.x;
    int ci = (b & 255) * 3 + (b >> 8);   // bijective [0,768)
    int n = ci >> 3;                     // same for co-resident blocks (mostly)
    int chunk = ci & 7;
    int s = chunk * 512 + threadIdx.x;
    const float* pr = params + (size_t)n * TP;

    float h[32];
    const float4* xv = (const float4*)(x + ((size_t)n * SS + s) * 32);
#pragma unroll
    for (int i = 0; i < 8; ++i) {
        float4 v = xv[i];
        h[4*i+0] = v.x; h[4*i+1] = v.y; h[4*i+2] = v.z; h[4*i+3] = v.w;
    }

#pragma unroll 1
    for (int L = 0; L < 3; ++L) {
        const float* lp = pr + L * 1056;
        float t[32];
#pragma unroll
        for (int e = 0; e < 32; ++e) t[e] = lp[e];          // bias (s_load)
#pragma unroll
        for (int d = 0; d < 32; ++d) {
            const float* wrow = lp + 32 + d * 32;
            float hd = h[d];
#pragma unroll
            for (int e = 0; e < 32; ++e)
                t[e] = fmaf(hd, wrow[e], t[e]);             // v_fma with s-operand
        }
#pragma unroll
        for (int e = 0; e < 32; ++e) h[e] = sin_w0(t[e]);
    }

    // last layer 32 -> 3, no activation
    const float* lp = pr + 3168;
    float t3[3];
#pragma unroll
    for (int e = 0; e < 3; ++e) t3[e] = lp[e];
#pragma unroll
    for (int d = 0; d < 32; ++d) {
        float hd = h[d];
#pragma unroll
        for (int e = 0; e < 3; ++e)
            t3[e] = fmaf(hd, lp[3 + d * 3 + e], t3[e]);
    }

    float* op = out + ((size_t)n * SS + s) * 3;
    op[0] = t3[0]; op[1] = t3[1]; op[2] = t3[2];
}

extern "C" void kernel_launch(void* const* d_in, const int* in_sizes, int n_in,
                              void* d_out, int out_size, void* d_ws, size_t ws_size,
                              hipStream_t stream)
{
    const float* x        = (const float*)d_in[0];
    const float* loc      = (const float*)d_in[1];
    const float* log_sc   = (const float*)d_in[2];
    const float* h_loc    = (const float*)d_in[3];
    const float* h_ls     = (const float*)d_in[4];
    const float* hh_loc   = (const float*)d_in[5];
    const float* hh_ls    = (const float*)d_in[6];
    const float* eps      = (const float*)d_in[7];
    const float* h_eps    = (const float*)d_in[8];
    const float* hh_eps   = (const float*)d_in[9];
    const float* W_map    = (const float*)d_in[10];
    const float* b_map    = (const float*)d_in[11];
    const int*   h_gi     = (const int*)d_in[12];
    const int*   hh_gi    = (const int*)d_in[13];
    float* out = (float*)d_out;

    // workspace layout (floats)
    float* zT       = (float*)d_ws;                       // 4096*96      = 393,216
    float* partials = zT + (size_t)PP * NN;               // 16*96*3267   = 5,018,112
    float* params   = partials + (size_t)KC_SPLIT * NN * TP; // 96*3267  = 313,632

    z_kernel<<<(NN * PP) / 256, 256, 0, stream>>>(
        loc, log_sc, h_loc, h_ls, hh_loc, hh_ls, eps, h_eps, hh_eps,
        h_gi, hh_gi, zT);

    gemm_kernel<<<NG * 208, 256, 0, stream>>>(W_map, zT, partials);

    reduce_kernel<<<(NN * TP + 255) / 256, 256, 0, stream>>>(partials, b_map, params);

    mlp_kernel<<<768, 512, 0, stream>>>(x, params, out);
}